// Round 15
// baseline (61.152 us; speedup 1.0000x reference)
//
#include <hip/hip_runtime.h>
#include <hip/hip_bf16.h>
#include <math.h>

// Problem constants
constexpr int B = 4, S = 4096, N = 16, D = 64, M = 4;
constexpr int SND = S * N * D;      // b stride for q/k/v (floats)
constexpr int ND  = N * D;          // s stride (floats)
constexpr int DD  = D * D;          // 4096
constexpr int NCH = 8;              // k1 chunks per bn
constexpr int SPB = S / NCH;        // 512 s per block
constexpr int NST = 16;             // stages of 32 rows

typedef __attribute__((ext_vector_type(8))) short bf16x8;
typedef __attribute__((ext_vector_type(4))) float f32x4;
typedef unsigned short u16;
typedef unsigned int u32;

__device__ inline u16 f2bf(float x) {
  __hip_bfloat16 h = __float2bfloat16(x);   // RNE
  return __builtin_bit_cast(u16, h);
}

// async global->LDS, 16B per lane; lds dest = wave-uniform base + lane*16
__device__ inline void gload16(const float* g, float* l) {
  __builtin_amdgcn_global_load_lds(
      (const __attribute__((address_space(1))) void*)g,
      (__attribute__((address_space(3))) void*)l, 16, 0, 0);
}

// ---------------------------------------------------------------------------
// Kernel 1: part[bn][ch] = sum_{s in chunk} K[s,:]^T ⊗ V[s,:]  via MFMA (bf16).
// r14 post-mortem: the stage-wait drained lgkmcnt(0) every barrier, which
// force-drains the async gload_lds queue -> ~1 load-latency per stage.
// Fixes: (1) vmcnt-ONLY counted waits (8 steady, 8->4->0 tail);
//        (2) 4 buffers, 3 stages prefetched ahead;
//        (3) bank-conflict-free compute reads via PRE-SWIZZLED global source
//            (gload_lds dest stays linear; src col-granule ^= (row>>3)&3;
//             read col-granule ^= lg). Frag values & C mapping = r6/r10.
// grid = (64 bn, 8 ch), block = 256 (4 waves). LDS 64KB -> 2 blocks/CU.
// ---------------------------------------------------------------------------
__global__ __launch_bounds__(256) void k1_partials(const float* __restrict__ kg,
                                                   const float* __restrict__ vg,
                                                   u16* __restrict__ part) {
  __shared__ float kbuf[4][32][64];   // 8KB per buffer
  __shared__ float vbuf[4][32][64];

  const int t = threadIdx.x, w = t >> 6, l = t & 63;
  const int lr = l & 15, lg = l >> 4;
  const int bn = blockIdx.x, ch = blockIdx.y;
  const int b = bn >> 4, n = bn & 15;
  const size_t base = (size_t)b * SND + (size_t)n * D;
  const int s0 = ch * SPB;

  f32x4 acc[4];
#pragma unroll
  for (int i = 0; i < 4; ++i) acc[i] = (f32x4)0.f;

  // Stage 32 rows; source column pre-swizzled so LDS holds
  // element K[s][4*a+b] at [row][(a ^ ((row>>3)&3))*4 + b].
#define STAGE(st, bi)                                                        \
  {                                                                          \
    _Pragma("unroll") for (int i = 0; i < 2; ++i) {                          \
      const int gid = (w * 2 + i) * 64 + l;        /* granule 0..511 */      \
      const int sl = gid >> 4;                     /* row 0..31 */           \
      const int cg = (gid & 15) ^ ((sl >> 3) & 3); /* swizzled src granule */\
      const float* gk = kg + base + (size_t)(s0 + (st) * 32 + sl) * ND + cg * 4; \
      const float* gv = vg + base + (size_t)(s0 + (st) * 32 + sl) * ND + cg * 4; \
      gload16(gk, &kbuf[bi][0][0] + (w * 2 + i) * 256);                      \
      gload16(gv, &vbuf[bi][0][0] + (w * 2 + i) * 256);                      \
    }                                                                        \
  }

  // read col 16*x+lr of row 8*lg+j: granule (4x + (lr>>2)) ^ lg, byte lr&3
#define COMPUTE(bi)                                                          \
  {                                                                          \
    bf16x8 af, bq[4];                                                        \
    _Pragma("unroll") for (int j = 0; j < 8; ++j)                            \
      af[j] = (short)f2bf(                                                   \
          kbuf[bi][8 * lg + j][(((4 * w + (lr >> 2)) ^ lg) << 2) + (lr & 3)]); \
    _Pragma("unroll") for (int ni = 0; ni < 4; ++ni)                         \
    _Pragma("unroll") for (int j = 0; j < 8; ++j)                            \
      bq[ni][j] = (short)f2bf(                                               \
          vbuf[bi][8 * lg + j][(((4 * ni + (lr >> 2)) ^ lg) << 2) + (lr & 3)]); \
    _Pragma("unroll") for (int ni = 0; ni < 4; ++ni)                         \
      acc[ni] = __builtin_amdgcn_mfma_f32_16x16x32_bf16(af, bq[ni],          \
                                                        acc[ni], 0, 0, 0);   \
  }

#define WAITBAR(n)                                                           \
  asm volatile("s_waitcnt vmcnt(" #n ")" ::: "memory");                      \
  __builtin_amdgcn_s_barrier();                                              \
  __builtin_amdgcn_sched_barrier(0);

  // prologue: 3 stages in flight (12 loads/wave), wait oldest stage landed
  STAGE(0, 0);
  STAGE(1, 1);
  STAGE(2, 2);
  WAITBAR(8);

#pragma unroll
  for (int st = 0; st < NST; ++st) {
    if (st + 3 < NST) STAGE(st + 3, (st + 3) & 3);
    COMPUTE(st & 3);
    if (st < NST - 3)       { WAITBAR(8); }   // stages st+2,st+3(,st+4) stay in flight
    else if (st == NST - 3) { WAITBAR(4); }
    else if (st == NST - 2) { WAITBAR(0); }
    // st == NST-1: done, no barrier needed
  }

#undef STAGE
#undef COMPUTE
#undef WAITBAR

  // bf16 partial store (r6/r10-verified C mapping)
  u16* p = part + ((size_t)bn * NCH + ch) * DD;
#pragma unroll
  for (int ni = 0; ni < 4; ++ni)
#pragma unroll
    for (int ri = 0; ri < 4; ++ri)
      p[(16 * w + 4 * lg + ri) * 64 + 16 * ni + lr] = f2bf(acc[ni][ri]);
}

// ---------------------------------------------------------------------------
// Kernel 2: Meff combine (part is bf16, NCH=8). Emits bf16 meffT[bn][v][k].
// grid = (64, 16), block = 256.
// ---------------------------------------------------------------------------
__global__ __launch_bounds__(256) void k2_combine(const u16* __restrict__ part,
                                                  const float* __restrict__ memg,
                                                  const float* __restrict__ decay,
                                                  const float* __restrict__ gatew,
                                                  u16* __restrict__ meffT) {
  const int t = threadIdx.x;
  const int bn = blockIdx.x;
  const int b = bn >> 4, n = bn & 15;
  const int kv = blockIdx.y * 256 + t;
  const int k = kv >> 6, v = kv & 63;

  float gw[M], df[M];
#pragma unroll
  for (int m = 0; m < M; ++m) { gw[m] = gatew[m]; df[m] = decay[m]; }
  const float mx = fmaxf(fmaxf(gw[0], gw[1]), fmaxf(gw[2], gw[3]));
  float e[M], esum = 0.f;
#pragma unroll
  for (int m = 0; m < M; ++m) { e[m] = expf(gw[m] - mx); esum += e[m]; }
  float wgt[M], cc = 0.f;
#pragma unroll
  for (int m = 0; m < M; ++m) {
    const float g = e[m] / esum;
    const float sg = 1.f / (1.f + expf(-df[m]));
    wgt[m] = g * sg;
    cc += g * (1.f - sg);
  }

  const u16* pb = part + (size_t)bn * NCH * DD + kv;
  float ni = 0.f;
#pragma unroll
  for (int ch = 0; ch < NCH; ++ch) {
    __hip_bfloat16 h = __builtin_bit_cast(__hip_bfloat16, pb[(size_t)ch * DD]);
    ni += __bfloat162float(h);
  }
  float a = cc * ni;
#pragma unroll
  for (int m = 0; m < M; ++m)
    a += wgt[m] * memg[(((size_t)b * M + m) * N + n) * DD + kv];

  meffT[(size_t)bn * DD + v * 64 + k] = f2bf(a);
}

// ---------------------------------------------------------------------------
// Kernel 3: out[s,v] = q[s,:] @ Meff  via MFMA, LDS-free, free-running.
// grid = (64 bn, 16), block = 256 (4 waves); wave handles 64 s-rows x 64 v.
// ---------------------------------------------------------------------------
__global__ __launch_bounds__(256, 4) void k3_out(const float* __restrict__ qg,
                                                 const u16* __restrict__ meffT,
                                                 float* __restrict__ outg) {
  const int t = threadIdx.x, w = t >> 6, l = t & 63;
  const int lr = l & 15, lg = l >> 4;
  const int bn = blockIdx.x;
  const int b = bn >> 4, n = bn & 15;
  const int s0 = blockIdx.y * 256 + w * 64;

  const u16* mb = meffT + (size_t)bn * DD;
  bf16x8 bfr[4][2];
#pragma unroll
  for (int ni = 0; ni < 4; ++ni)
#pragma unroll
    for (int ks = 0; ks < 2; ++ks)
      bfr[ni][ks] = *(const bf16x8*)(mb + (16 * ni + lr) * 64 + 32 * ks + 8 * lg);

  f32x4 acc[4][4];
#pragma unroll
  for (int i = 0; i < 4; ++i)
#pragma unroll
    for (int j = 0; j < 4; ++j) acc[i][j] = (f32x4)0.f;

  const size_t qbase = (size_t)b * SND + (size_t)n * D;

#pragma unroll
  for (int mi = 0; mi < 4; ++mi) {
    const float* qr = qg + qbase + (size_t)(s0 + 16 * mi + lr) * ND + 8 * lg;
#pragma unroll
    for (int ks = 0; ks < 2; ++ks) {
      float qa[8];
      *(float4*)&qa[0] = *(const float4*)(qr + 32 * ks);
      *(float4*)&qa[4] = *(const float4*)(qr + 32 * ks + 4);
      bf16x8 a;
#pragma unroll
      for (int j = 0; j < 8; ++j) a[j] = (short)f2bf(qa[j]);
#pragma unroll
      for (int ni = 0; ni < 4; ++ni)
        acc[mi][ni] = __builtin_amdgcn_mfma_f32_16x16x32_bf16(a, bfr[ni][ks],
                                                              acc[mi][ni], 0, 0, 0);
    }
  }

#pragma unroll
  for (int mi = 0; mi < 4; ++mi)
#pragma unroll
    for (int ni = 0; ni < 4; ++ni)
#pragma unroll
      for (int ri = 0; ri < 4; ++ri)
        outg[qbase + (size_t)(s0 + 16 * mi + 4 * lg + ri) * ND + 16 * ni + lr] =
            acc[mi][ni][ri];
}

// ---------------------------------------------------------------------------
extern "C" void kernel_launch(void* const* d_in, const int* in_sizes, int n_in,
                              void* d_out, int out_size, void* d_ws, size_t ws_size,
                              hipStream_t stream) {
  const float* q     = (const float*)d_in[0];
  const float* k     = (const float*)d_in[1];
  const float* v     = (const float*)d_in[2];
  const float* memg  = (const float*)d_in[3];
  const float* decay = (const float*)d_in[4];
  const float* gatew = (const float*)d_in[5];
  float* out = (float*)d_out;

  u16* meffT = (u16*)d_ws;                            // 512 KB
  const size_t meffT_bytes = (size_t)64 * DD * sizeof(u16);
  u16* part = (u16*)((char*)d_ws + meffT_bytes);      // 4 MB bf16 partials

  hipLaunchKernelGGL(k1_partials, dim3(64, NCH), dim3(256), 0, stream,
                     k, v, part);
  hipLaunchKernelGGL(k2_combine, dim3(64, 16), dim3(256), 0, stream,
                     part, memg, decay, gatew, meffT);
  hipLaunchKernelGGL(k3_out, dim3(64, 16), dim3(256), 0, stream,
                     q, meffT, out);
}

// Round 16
// 60.280 us; speedup vs baseline: 1.0145x; 1.0145x over previous
//
#include <hip/hip_runtime.h>
#include <hip/hip_bf16.h>
#include <math.h>

// Problem constants
constexpr int B = 4, S = 4096, N = 16, D = 64, M = 4;
constexpr int SND = S * N * D;      // b stride for q/k/v (floats)
constexpr int ND  = N * D;          // s stride (floats)
constexpr int DD  = D * D;          // 4096
constexpr int NCH = 8;              // k1 chunks per bn
constexpr int SPB = S / NCH;        // 512 s per block
constexpr int NST = 32;             // stages of 16 rows

typedef __attribute__((ext_vector_type(8))) short bf16x8;
typedef __attribute__((ext_vector_type(4))) float f32x4;
typedef unsigned short u16;
typedef unsigned int u32;

__device__ inline u16 f2bf(float x) {
  __hip_bfloat16 h = __float2bfloat16(x);   // RNE
  return __builtin_bit_cast(u16, h);
}

// async global->LDS, 16B per lane; lds dest = wave-uniform base + lane*16
__device__ inline void gload16(const float* g, float* l) {
  __builtin_amdgcn_global_load_lds(
      (const __attribute__((address_space(1))) void*)g,
      (__attribute__((address_space(3))) void*)l, 16, 0, 0);
}

// ---------------------------------------------------------------------------
// Kernel 1: part[bn][ch] = sum_{s in chunk} K[s,:]^T ⊗ V[s,:]  via MFMA (bf16).
// SINGLE-KNOB EXPERIMENT vs r15: prefetch depth 3 -> 7 stage-latencies.
//   - 16-row stages (8 KB: 4KB k + 4KB v), 8 buffers = 64 KB LDS
//   - 7 stages in flight: 14 outstanding gload16/wave, steady vmcnt(10)
//   - STAGE issued AFTER the barrier (pair-overwrite race-free)
//   - COMPUTE on aligned buffer pairs (K=32): lane-term (lg>>1)*1024 picks
//     the half; fragment values & C mapping identical to r6/r10 verified.
// grid = (64 bn, 8 ch), block = 256 (4 waves). 2 blocks/CU.
// ---------------------------------------------------------------------------
__global__ __launch_bounds__(256) void k1_partials(const float* __restrict__ kg,
                                                   const float* __restrict__ vg,
                                                   u16* __restrict__ part) {
  __shared__ float kbuf[8][16][64];   // 4 KB per buffer
  __shared__ float vbuf[8][16][64];

  const int t = threadIdx.x, w = t >> 6, l = t & 63;
  const int lr = l & 15, lg = l >> 4;
  const int bn = blockIdx.x, ch = blockIdx.y;
  const int b = bn >> 4, n = bn & 15;
  const size_t base = (size_t)b * SND + (size_t)n * D;
  const int s0 = ch * SPB;

  f32x4 acc[4];
#pragma unroll
  for (int i = 0; i < 4; ++i) acc[i] = (f32x4)0.f;

  // wave w stages rows 4w..4w+3 of the 16-row stage; 1 gload16 per tensor
#define STAGE(st, bi)                                                        \
  {                                                                          \
    const int sl = 4 * w + (l >> 4), cf = (l & 15) * 4;                      \
    const float* gk = kg + base + (size_t)(s0 + (st) * 16 + sl) * ND + cf;   \
    const float* gv = vg + base + (size_t)(s0 + (st) * 16 + sl) * ND + cf;   \
    gload16(gk, &kbuf[bi][0][0] + w * 256);                                  \
    gload16(gv, &vbuf[bi][0][0] + w * 256);                                  \
  }

  // K=32 compute over buffer pair (biA even, biA+1):
  // s = 16*(lg>>1) + 8*(lg&1) + j ; af[j]=K[s][16w+lr], bq[ni][j]=V[s][16ni+lr]
#define COMPUTE(biA)                                                         \
  {                                                                          \
    const float* kb = &kbuf[biA][0][0];                                      \
    const float* vb = &vbuf[biA][0][0];                                      \
    const int lo = (lg >> 1) * 1024 + (8 * (lg & 1)) * 64;                   \
    bf16x8 af, bq[4];                                                        \
    _Pragma("unroll") for (int j = 0; j < 8; ++j)                            \
      af[j] = (short)f2bf(kb[lo + j * 64 + 16 * w + lr]);                    \
    _Pragma("unroll") for (int ni = 0; ni < 4; ++ni)                         \
    _Pragma("unroll") for (int j = 0; j < 8; ++j)                            \
      bq[ni][j] = (short)f2bf(vb[lo + j * 64 + 16 * ni + lr]);               \
    _Pragma("unroll") for (int ni = 0; ni < 4; ++ni)                         \
      acc[ni] = __builtin_amdgcn_mfma_f32_16x16x32_bf16(af, bq[ni],          \
                                                        acc[ni], 0, 0, 0);   \
  }

#define WAITBAR(nlit)                                                        \
  asm volatile("s_waitcnt vmcnt(" #nlit ")" ::: "memory");                   \
  __builtin_amdgcn_s_barrier();                                              \
  __builtin_amdgcn_sched_barrier(0);

  // prologue: 7 stages in flight (14 loads/wave); stage 0 landed after wait
  STAGE(0, 0); STAGE(1, 1); STAGE(2, 2); STAGE(3, 3);
  STAGE(4, 4); STAGE(5, 5); STAGE(6, 6);
  WAITBAR(12);

#pragma unroll
  for (int st = 0; st < NST; ++st) {
    if (st & 1) COMPUTE((st - 1) & 7);
    // wait: stage st+1 landed; barrier releases pair buffer for overwrite
    if      (st <= 25) { WAITBAR(10); }
    else if (st == 26) { WAITBAR(8); }
    else if (st == 27) { WAITBAR(6); }
    else if (st == 28) { WAITBAR(4); }
    else if (st == 29) { WAITBAR(2); }
    else if (st == 30) { WAITBAR(0); }
    if (st + 7 < NST) STAGE(st + 7, (st + 7) & 7);
  }

#undef STAGE
#undef COMPUTE
#undef WAITBAR

  // bf16 partial store (r6/r10-verified C mapping)
  u16* p = part + ((size_t)bn * NCH + ch) * DD;
#pragma unroll
  for (int ni = 0; ni < 4; ++ni)
#pragma unroll
    for (int ri = 0; ri < 4; ++ri)
      p[(16 * w + 4 * lg + ri) * 64 + 16 * ni + lr] = f2bf(acc[ni][ri]);
}

// ---------------------------------------------------------------------------
// Kernel 2: Meff combine (part is bf16, NCH=8). Emits bf16 meffT[bn][v][k].
// grid = (64, 16), block = 256.
// ---------------------------------------------------------------------------
__global__ __launch_bounds__(256) void k2_combine(const u16* __restrict__ part,
                                                  const float* __restrict__ memg,
                                                  const float* __restrict__ decay,
                                                  const float* __restrict__ gatew,
                                                  u16* __restrict__ meffT) {
  const int t = threadIdx.x;
  const int bn = blockIdx.x;
  const int b = bn >> 4, n = bn & 15;
  const int kv = blockIdx.y * 256 + t;
  const int k = kv >> 6, v = kv & 63;

  float gw[M], df[M];
#pragma unroll
  for (int m = 0; m < M; ++m) { gw[m] = gatew[m]; df[m] = decay[m]; }
  const float mx = fmaxf(fmaxf(gw[0], gw[1]), fmaxf(gw[2], gw[3]));
  float e[M], esum = 0.f;
#pragma unroll
  for (int m = 0; m < M; ++m) { e[m] = expf(gw[m] - mx); esum += e[m]; }
  float wgt[M], cc = 0.f;
#pragma unroll
  for (int m = 0; m < M; ++m) {
    const float g = e[m] / esum;
    const float sg = 1.f / (1.f + expf(-df[m]));
    wgt[m] = g * sg;
    cc += g * (1.f - sg);
  }

  const u16* pb = part + (size_t)bn * NCH * DD + kv;
  float ni = 0.f;
#pragma unroll
  for (int ch = 0; ch < NCH; ++ch) {
    __hip_bfloat16 h = __builtin_bit_cast(__hip_bfloat16, pb[(size_t)ch * DD]);
    ni += __bfloat162float(h);
  }
  float a = cc * ni;
#pragma unroll
  for (int m = 0; m < M; ++m)
    a += wgt[m] * memg[(((size_t)b * M + m) * N + n) * DD + kv];

  meffT[(size_t)bn * DD + v * 64 + k] = f2bf(a);
}

// ---------------------------------------------------------------------------
// Kernel 3: out[s,v] = q[s,:] @ Meff  via MFMA, LDS-free, free-running.
// grid = (64 bn, 16), block = 256 (4 waves); wave handles 64 s-rows x 64 v.
// ---------------------------------------------------------------------------
__global__ __launch_bounds__(256, 4) void k3_out(const float* __restrict__ qg,
                                                 const u16* __restrict__ meffT,
                                                 float* __restrict__ outg) {
  const int t = threadIdx.x, w = t >> 6, l = t & 63;
  const int lr = l & 15, lg = l >> 4;
  const int bn = blockIdx.x;
  const int b = bn >> 4, n = bn & 15;
  const int s0 = blockIdx.y * 256 + w * 64;

  const u16* mb = meffT + (size_t)bn * DD;
  bf16x8 bfr[4][2];
#pragma unroll
  for (int ni = 0; ni < 4; ++ni)
#pragma unroll
    for (int ks = 0; ks < 2; ++ks)
      bfr[ni][ks] = *(const bf16x8*)(mb + (16 * ni + lr) * 64 + 32 * ks + 8 * lg);

  f32x4 acc[4][4];
#pragma unroll
  for (int i = 0; i < 4; ++i)
#pragma unroll
    for (int j = 0; j < 4; ++j) acc[i][j] = (f32x4)0.f;

  const size_t qbase = (size_t)b * SND + (size_t)n * D;

#pragma unroll
  for (int mi = 0; mi < 4; ++mi) {
    const float* qr = qg + qbase + (size_t)(s0 + 16 * mi + lr) * ND + 8 * lg;
#pragma unroll
    for (int ks = 0; ks < 2; ++ks) {
      float qa[8];
      *(float4*)&qa[0] = *(const float4*)(qr + 32 * ks);
      *(float4*)&qa[4] = *(const float4*)(qr + 32 * ks + 4);
      bf16x8 a;
#pragma unroll
      for (int j = 0; j < 8; ++j) a[j] = (short)f2bf(qa[j]);
#pragma unroll
      for (int ni = 0; ni < 4; ++ni)
        acc[mi][ni] = __builtin_amdgcn_mfma_f32_16x16x32_bf16(a, bfr[ni][ks],
                                                              acc[mi][ni], 0, 0, 0);
    }
  }

#pragma unroll
  for (int mi = 0; mi < 4; ++mi)
#pragma unroll
    for (int ni = 0; ni < 4; ++ni)
#pragma unroll
      for (int ri = 0; ri < 4; ++ri)
        outg[qbase + (size_t)(s0 + 16 * mi + 4 * lg + ri) * ND + 16 * ni + lr] =
            acc[mi][ni][ri];
}

// ---------------------------------------------------------------------------
extern "C" void kernel_launch(void* const* d_in, const int* in_sizes, int n_in,
                              void* d_out, int out_size, void* d_ws, size_t ws_size,
                              hipStream_t stream) {
  const float* q     = (const float*)d_in[0];
  const float* k     = (const float*)d_in[1];
  const float* v     = (const float*)d_in[2];
  const float* memg  = (const float*)d_in[3];
  const float* decay = (const float*)d_in[4];
  const float* gatew = (const float*)d_in[5];
  float* out = (float*)d_out;

  u16* meffT = (u16*)d_ws;                            // 512 KB
  const size_t meffT_bytes = (size_t)64 * DD * sizeof(u16);
  u16* part = (u16*)((char*)d_ws + meffT_bytes);      // 4 MB bf16 partials

  hipLaunchKernelGGL(k1_partials, dim3(64, NCH), dim3(256), 0, stream,
                     k, v, part);
  hipLaunchKernelGGL(k2_combine, dim3(64, 16), dim3(256), 0, stream,
                     part, memg, decay, gatew, meffT);
  hipLaunchKernelGGL(k3_out, dim3(64, 16), dim3(256), 0, stream,
                     q, meffT, out);
}